// Round 4
// baseline (275.702 us; speedup 1.0000x reference)
//
#include <hip/hip_runtime.h>
#include <hip/hip_bf16.h>

#define B_  4
#define T_  2048
#define D_  768
#define H_  12
#define DH_ 64
#define FF_ 3072

typedef __attribute__((ext_vector_type(8))) short bf16x8;
typedef __attribute__((ext_vector_type(4))) float f32x4;
typedef __attribute__((ext_vector_type(4))) unsigned short us4;

#define MFMA16(a, b, c) __builtin_amdgcn_mfma_f32_16x16x32_bf16((a), (b), (c), 0, 0, 0)

__device__ __forceinline__ unsigned short f2bf(float f) {
    union { float f; unsigned u; } v; v.f = f;
    unsigned r = v.u + 0x7fffu + ((v.u >> 16) & 1u);
    return (unsigned short)(r >> 16);
}

// async global->LDS, 16B per lane. LDS dest must be wave-uniform; HW adds lane*16.
__device__ __forceinline__ void gload_lds16(const unsigned short* gp, unsigned short* lp) {
    __builtin_amdgcn_global_load_lds(
        (const __attribute__((address_space(1))) unsigned int*)gp,
        (__attribute__((address_space(3))) unsigned int*)lp,
        16, 0, 0);
}

// ---------------- weight convert + transpose: src[K][N] f32 -> dst[N][K] bf16 ----------
__global__ __launch_bounds__(256) void tcvt_kernel(
    const float* __restrict__ src, unsigned short* __restrict__ dst, int K, int N)
{
    __shared__ float tile[32][33];
    const int bx = blockIdx.x * 32;  // N dim
    const int by = blockIdx.y * 32;  // K dim
    const int tx = threadIdx.x, ty = threadIdx.y;  // 32 x 8
#pragma unroll
    for (int i = 0; i < 32; i += 8)
        tile[ty + i][tx] = src[(size_t)(by + ty + i) * N + bx + tx];
    __syncthreads();
#pragma unroll
    for (int i = 0; i < 32; i += 8)
        dst[(size_t)(bx + ty + i) * K + by + tx] = f2bf(tile[tx][ty + i]);
}

// batched version for the four 768x768 weights (Wq,Wk,Wv,Wo -> contiguous dst)
__global__ __launch_bounds__(256) void tcvt4_kernel(
    const float* __restrict__ s0, const float* __restrict__ s1,
    const float* __restrict__ s2, const float* __restrict__ s3,
    unsigned short* __restrict__ dst)
{
    __shared__ float tile[32][33];
    const int z = blockIdx.z;
    const float* src = (z == 0) ? s0 : (z == 1) ? s1 : (z == 2) ? s2 : s3;
    unsigned short* d = dst + (size_t)z * 589824;
    const int bx = blockIdx.x * 32;
    const int by = blockIdx.y * 32;
    const int tx = threadIdx.x, ty = threadIdx.y;
#pragma unroll
    for (int i = 0; i < 32; i += 8)
        tile[ty + i][tx] = src[(size_t)(by + ty + i) * 768 + bx + tx];
    __syncthreads();
#pragma unroll
    for (int i = 0; i < 32; i += 8)
        d[(size_t)(bx + ty + i) * 768 + by + tx] = f2bf(tile[tx][ty + i]);
}

// ---------------- LayerNorm: fp32 in -> bf16 out ----------------
__global__ __launch_bounds__(256) void ln_kernel(
    const float* __restrict__ x, const float* __restrict__ g,
    const float* __restrict__ be, unsigned short* __restrict__ out)
{
    const int row = blockIdx.x;
    const int t = threadIdx.x;
    const float* xr = x + (size_t)row * D_;
    float v0 = xr[t], v1 = xr[t + 256], v2 = xr[t + 512];
    float s = v0 + v1 + v2;
    float s2 = v0 * v0 + v1 * v1 + v2 * v2;
#pragma unroll
    for (int o = 1; o < 64; o <<= 1) {
        s  += __shfl_xor(s,  o);
        s2 += __shfl_xor(s2, o);
    }
    __shared__ float rs[4], rq[4];
    const int wave = t >> 6;
    if ((t & 63) == 0) { rs[wave] = s; rq[wave] = s2; }
    __syncthreads();
    s  = rs[0] + rs[1] + rs[2] + rs[3];
    s2 = rq[0] + rq[1] + rq[2] + rq[3];
    const float mu = s * (1.0f / D_);
    const float var = s2 * (1.0f / D_) - mu * mu;
    const float rstd = rsqrtf(var + 1e-5f);
    unsigned short* orow = out + (size_t)row * D_;
    orow[t]       = f2bf((v0 - mu) * rstd * g[t]       + be[t]);
    orow[t + 256] = f2bf((v1 - mu) * rstd * g[t + 256] + be[t + 256]);
    orow[t + 512] = f2bf((v2 - mu) * rstd * g[t + 512] + be[t + 512]);
}

// ---------------- GEMM: C[M][N] = A[M][K] * Bt[N][K]^T + bias ----------------
// BM=128, BN=128, BK=64; 512 threads (8 waves as 4x2), wave-tile 32x64 (acc 2x4).
// TRI-BUFFERED pipeline (prefetch depth 2): raw s_barrier + counted vmcnt(4)
// (each wave's own 4 staging loads per tile; next tile's 4 stay in flight
// across the barrier). One barrier per K-tile. lgkmcnt(0)+sched_barrier before
// the MFMA cluster; setprio(1) around it.
// LDS tiles XOR-swizzled at 16B granularity via pre-swizzled global SOURCE
// (gload_lds dest stays linear); ds_read applies the same XOR. Conflict-free.
// 1D grid, N-fastest, bijective XCD swizzle.
// MODE 0: bf16 out; MODE 2: gelu->bf16; MODE 3: fp32 = acc+bias+resid;
// MODE 4: fused QKV routing (Q,K bf16 [M][768]; V transposed out3[b][n][t]).
template<int MODE>
__global__ __launch_bounds__(512) void gemm512(
    const unsigned short* __restrict__ A,
    const unsigned short* __restrict__ Bt,
    const float* __restrict__ bias,
    const float* __restrict__ bias2,
    const float* __restrict__ bias3,
    const float* __restrict__ resid,
    void* __restrict__ outp,
    void* __restrict__ out2,
    void* __restrict__ out3,
    int N, int K, int nTilesN)
{
    extern __shared__ __align__(16) unsigned short lds[];   // 3 x (A 8192 + B 8192) shorts = 96KB

    // bijective XCD swizzle (m204)
    const int nwg = gridDim.x;
    const int q = nwg >> 3, rr = nwg & 7;
    const int xcd = blockIdx.x & 7, loc = blockIdx.x >> 3;
    const int swz = (xcd < rr ? xcd * (q + 1) : rr * (q + 1) + (xcd - rr) * q) + loc;
    const int m0 = (swz / nTilesN) * 128;
    const int n0 = (swz % nTilesN) * 128;

    const int tid = threadIdx.x;
    const int wv = tid >> 6;
    const int lane = tid & 63;
    const int wr = wv >> 1;          // 0..3
    const int wc = wv & 1;           // 0..1

    f32x4 zero4 = {0.0f, 0.0f, 0.0f, 0.0f};
    f32x4 acc[2][4];
#pragma unroll
    for (int i = 0; i < 2; ++i)
#pragma unroll
        for (int j = 0; j < 4; ++j) acc[i][j] = zero4;

    // staging: each wave stages 16 rows (2 issues x 8 rows) of A and of B.
    // lane -> (row=lane>>3, blk=lane&7); source col-block = blk ^ (row&7)
    const int lrow = lane >> 3;
    const int scb = (lane & 7) ^ lrow;
    const size_t ag0 = (size_t)(m0 + wv * 16 + lrow) * K + scb * 8;
    const size_t ag1 = ag0 + (size_t)8 * K;
    const size_t bg0 = (size_t)(n0 + wv * 16 + lrow) * K + scb * 8;
    const size_t bg1 = bg0 + (size_t)8 * K;
    const int woff = wv * 1024;

    const int fr = lane & 15;        // fragment row within 16
    const int fg = lane >> 4;        // 0..3 col-block group
    const int sw = fr & 7;           // XOR key for ds_read

    unsigned short* pc = lds;                // compute buffer (tile t)
    unsigned short* pn = lds + 16384;        // next (tile t+1)
    unsigned short* ps = lds + 32768;        // stage target (tile t+2)

    const int nk = K >> 6;

    // prologue: stage tiles 0 and 1
    {
        gload_lds16(A  + ag0, pc + woff);
        gload_lds16(A  + ag1, pc + woff + 512);
        gload_lds16(Bt + bg0, pc + 8192 + woff);
        gload_lds16(Bt + bg1, pc + 8192 + woff + 512);
        if (nk > 1) {
            const int k0 = 64;
            gload_lds16(A  + ag0 + k0, pn + woff);
            gload_lds16(A  + ag1 + k0, pn + woff + 512);
            gload_lds16(Bt + bg0 + k0, pn + 8192 + woff);
            gload_lds16(Bt + bg1 + k0, pn + 8192 + woff + 512);
        }
    }

    for (int t = 0; t < nk; ++t) {
        // wait own tile-t loads (4 of t+1's may remain in flight), then sync all waves
        if (t < nk - 1) asm volatile("s_waitcnt vmcnt(4)" ::: "memory");
        else            asm volatile("s_waitcnt vmcnt(0)" ::: "memory");
        __builtin_amdgcn_s_barrier();
        asm volatile("" ::: "memory");

        // stage tile t+2 into ps (read out 1 barrier ago; WAR-safe)
        if (t + 2 < nk) {
            const int k0 = (t + 2) << 6;
            gload_lds16(A  + ag0 + k0, ps + woff);
            gload_lds16(A  + ag1 + k0, ps + woff + 512);
            gload_lds16(Bt + bg0 + k0, ps + 8192 + woff);
            gload_lds16(Bt + bg1 + k0, ps + 8192 + woff + 512);
        }

        // fragment loads from pc
        bf16x8 afr[2][2], bfr[2][4];
#pragma unroll
        for (int kk = 0; kk < 2; ++kk) {
#pragma unroll
            for (int mm = 0; mm < 2; ++mm) {
                const int row = wr * 32 + mm * 16 + fr;
                afr[kk][mm] = *(const bf16x8*)(pc + row * 64 + (((kk * 4 + fg) ^ sw) << 3));
            }
#pragma unroll
            for (int nn = 0; nn < 4; ++nn) {
                const int row = wc * 64 + nn * 16 + fr;
                bfr[kk][nn] = *(const bf16x8*)(pc + 8192 + row * 64 + (((kk * 4 + fg) ^ sw) << 3));
            }
        }
        asm volatile("s_waitcnt lgkmcnt(0)" ::: "memory");
        __builtin_amdgcn_sched_barrier(0);
        __builtin_amdgcn_s_setprio(1);
#pragma unroll
        for (int kk = 0; kk < 2; ++kk)
#pragma unroll
            for (int mm = 0; mm < 2; ++mm)
#pragma unroll
                for (int nn = 0; nn < 4; ++nn)
                    acc[mm][nn] = MFMA16(afr[kk][mm], bfr[kk][nn], acc[mm][nn]);
        __builtin_amdgcn_s_setprio(0);

        // rotate buffers
        unsigned short* tmp = pc; pc = pn; pn = ps; ps = tmp;
    }

    const int lc = lane & 15;
    const int lr = (lane >> 4) * 4;
#pragma unroll
    for (int mm = 0; mm < 2; ++mm) {
        const int gm0 = m0 + wr * 32 + mm * 16 + lr;
#pragma unroll
        for (int nn = 0; nn < 4; ++nn) {
            const int gn = n0 + wc * 64 + nn * 16 + lc;
            if (MODE == 4) {
                if (gn < 1536) {
                    const float bv = (gn < 768) ? bias[gn] : bias2[gn - 768];
                    unsigned short* o = (gn < 768) ? (unsigned short*)outp : (unsigned short*)out2;
                    const int col = (gn < 768) ? gn : gn - 768;
#pragma unroll
                    for (int r = 0; r < 4; ++r)
                        o[(size_t)(gm0 + r) * 768 + col] = f2bf(acc[mm][nn][r] + bv);
                } else {
                    const float bv = bias3[gn - 1536];
                    const int b = gm0 / T_;
                    const int tl = gm0 - b * T_;
                    us4 pk;
#pragma unroll
                    for (int r = 0; r < 4; ++r) pk[r] = f2bf(acc[mm][nn][r] + bv);
                    *(us4*)((unsigned short*)out3 + ((size_t)(b * D_ + gn - 1536)) * T_ + tl) = pk;
                }
            } else {
                const float bv = bias[gn];
#pragma unroll
                for (int r = 0; r < 4; ++r) {
                    const int gm = gm0 + r;
                    float v = acc[mm][nn][r] + bv;
                    if (MODE == 0) {
                        ((unsigned short*)outp)[(size_t)gm * N + gn] = f2bf(v);
                    } else if (MODE == 2) {
                        v = 0.5f * v * (1.0f + erff(v * 0.70710678118654752f));
                        ((unsigned short*)outp)[(size_t)gm * N + gn] = f2bf(v);
                    } else if (MODE == 3) {
                        ((float*)outp)[(size_t)gm * N + gn] = v + resid[(size_t)gm * N + gn];
                    }
                }
            }
        }
    }
}

// ---------------- banded flash attention ----------------
// block = 256 threads (4 waves), handles (b, h, 64-query tile)
// K/V window = [t0, t1), KW <= 192
__global__ __launch_bounds__(256) void attn_kernel(
    const unsigned short* __restrict__ Q,    // [B*T][768]
    const unsigned short* __restrict__ Kg,   // [B*T][768]
    const unsigned short* __restrict__ Vt,   // [B][768][T]
    unsigned short* __restrict__ ctx)        // [B*T][768]
{
    __shared__ __align__(16) unsigned short Qs[64][72];
    __shared__ __align__(16) unsigned short KP[192 * 72];   // Ks[192][72], later Ps[64][200]
    __shared__ __align__(16) unsigned short Vts[64][200];

    const int tid = threadIdx.x;
    const int lane = tid & 63;
    const int w = tid >> 6;
    const int bid = blockIdx.x;
    const int qt = bid & 31;
    const int h = (bid >> 5) % H_;
    const int b = bid / (32 * H_);
    const int qs = qt * 64;
    const int t0 = qs >= 64 ? qs - 64 : 0;
    const int t1 = (qs + 128 < T_) ? qs + 128 : T_;
    const int KW = t1 - t0;

    // stage Q (64 rows x 64 cols)
    for (int s = tid; s < 512; s += 256) {
        const int r = s >> 3, c8 = (s & 7) << 3;
        *(uint4*)&Qs[r][c8] =
            *(const uint4*)&Q[((size_t)(b * T_ + qs + r)) * D_ + h * DH_ + c8];
    }
    // stage K (192 rows x 64), zero-filled beyond window
    unsigned short* Ks = KP;
    for (int s = tid; s < 1536; s += 256) {
        const int r = s >> 3, c8 = (s & 7) << 3;
        uint4 val = {0, 0, 0, 0};
        if (r < KW)
            val = *(const uint4*)&Kg[((size_t)(b * T_ + t0 + r)) * D_ + h * DH_ + c8];
        *(uint4*)&Ks[r * 72 + c8] = val;
    }
    // stage V^T (64 dh-rows x 192 key-cols), zero-filled beyond window
    for (int s = tid; s < 1536; s += 256) {
        const int r = s / 24, c8 = (s % 24) << 3;
        uint4 val = {0, 0, 0, 0};
        if (c8 < KW)
            val = *(const uint4*)&Vt[((size_t)((b * H_ + h) * DH_ + r)) * T_ + t0 + c8];
        *(uint4*)&Vts[r][c8] = val;
    }
    __syncthreads();

    // S = Q K^T : per wave 16 q-rows x 192 keys, 12 col-frags, K=64 (2 ksteps)
    f32x4 zero4 = {0.0f, 0.0f, 0.0f, 0.0f};
    f32x4 sa[12];
#pragma unroll
    for (int i = 0; i < 12; ++i) sa[i] = zero4;
#pragma unroll
    for (int ks = 0; ks < 2; ++ks) {
        const bf16x8 aq = *(const bf16x8*)&Qs[w * 16 + (lane & 15)][ks * 32 + (lane >> 4) * 8];
#pragma unroll
        for (int cf = 0; cf < 12; ++cf) {
            const bf16x8 bk = *(const bf16x8*)&Ks[(cf * 16 + (lane & 15)) * 72 + ks * 32 + (lane >> 4) * 8];
            sa[cf] = MFMA16(aq, bk, sa[cf]);
        }
    }
    __syncthreads();   // everyone done reading Ks before Ps overwrites it

    // mask + softmax (row = q, spread over 16 lanes x 12 frags)
    const int lq = w * 16 + (lane >> 4) * 4;
    float mx[4] = {-1e30f, -1e30f, -1e30f, -1e30f};
#pragma unroll
    for (int cf = 0; cf < 12; ++cf) {
        const int key = t0 + cf * 16 + (lane & 15);
#pragma unroll
        for (int r = 0; r < 4; ++r) {
            const int dd = (qs + lq + r) - key;
            const bool ok = (key < t1) && (dd <= 64) && (dd >= -64);
            const float sv = ok ? sa[cf][r] * 0.125f : -1e30f;
            sa[cf][r] = sv;
            mx[r] = fmaxf(mx[r], sv);
        }
    }
#pragma unroll
    for (int r = 0; r < 4; ++r)
#pragma unroll
        for (int o = 1; o < 16; o <<= 1)
            mx[r] = fmaxf(mx[r], __shfl_xor(mx[r], o));

    unsigned short* Ps = KP;   // [64][200]
    float sm[4] = {0.0f, 0.0f, 0.0f, 0.0f};
#pragma unroll
    for (int cf = 0; cf < 12; ++cf) {
#pragma unroll
        for (int r = 0; r < 4; ++r) {
            const float p = __expf(sa[cf][r] - mx[r]);   // masked -> 0
            sm[r] += p;
            Ps[(lq + r) * 200 + cf * 16 + (lane & 15)] = f2bf(p);
        }
    }
#pragma unroll
    for (int r = 0; r < 4; ++r)
#pragma unroll
        for (int o = 1; o < 16; o <<= 1)
            sm[r] += __shfl_xor(sm[r], o);

    // O = P V : per wave 16 q-rows x 64 dh, 4 col-frags, K=192 (6 ksteps)
    f32x4 oa[4];
#pragma unroll
    for (int i = 0; i < 4; ++i) oa[i] = zero4;
#pragma unroll
    for (int ks = 0; ks < 6; ++ks) {
        const bf16x8 ap = *(const bf16x8*)&Ps[(w * 16 + (lane & 15)) * 200 + ks * 32 + (lane >> 4) * 8];
#pragma unroll
        for (int nf = 0; nf < 4; ++nf) {
            const bf16x8 bv = *(const bf16x8*)&Vts[nf * 16 + (lane & 15)][ks * 32 + (lane >> 4) * 8];
            oa[nf] = MFMA16(ap, bv, oa[nf]);
        }
    }
#pragma unroll
    for (int nf = 0; nf < 4; ++nf) {
#pragma unroll
        for (int r = 0; r < 4; ++r) {
            const float o = oa[nf][r] / sm[r];
            ctx[((size_t)(b * T_ + qs + lq + r)) * D_ + h * DH_ + nf * 16 + (lane & 15)] = f2bf(o);
        }
    }
}

// ---------------- orchestration ----------------
extern "C" void kernel_launch(void* const* d_in, const int* in_sizes, int n_in,
                              void* d_out, int out_size, void* d_ws, size_t ws_size,
                              hipStream_t stream)
{
    const float* x   = (const float*)d_in[0];
    const float* Wq  = (const float*)d_in[1];
    const float* bq  = (const float*)d_in[2];
    const float* Wk  = (const float*)d_in[3];
    const float* bk  = (const float*)d_in[4];
    const float* Wv  = (const float*)d_in[5];
    const float* bv  = (const float*)d_in[6];
    const float* Wo  = (const float*)d_in[7];
    const float* bo  = (const float*)d_in[8];
    const float* W1  = (const float*)d_in[9];
    const float* b1  = (const float*)d_in[10];
    const float* W2  = (const float*)d_in[11];
    const float* b2  = (const float*)d_in[12];
    const float* g1  = (const float*)d_in[13];
    const float* be1 = (const float*)d_in[14];
    const float* g2  = (const float*)d_in[15];
    const float* be2 = (const float*)d_in[16];
    float* out = (float*)d_out;

    // workspace layout (elements):
    // wqkv_t [2304][768] bf16, wo_t, w1_t, w2_t | hbuf | qbuf | x2 f32 | kbuf | vtb | ffb over kbuf..
    unsigned short* wqkv_t = (unsigned short*)d_ws;        // 3 x [768][768]
    unsigned short* wo_t = wqkv_t + 3 * 589824;
    unsigned short* w1_t = wo_t + 589824;                  // [3072][768]
    unsigned short* w2_t = w1_t + 2359296;                 // [768][3072]
    unsigned short* hbuf = w2_t + 2359296;                 // h1, later ctx
    unsigned short* qbuf = hbuf + 6291456;                 // q, later h2
    float* x2 = (float*)(qbuf + 6291456);                  // fp32 [8192][768]
    unsigned short* kbuf = (unsigned short*)(x2 + 6291456);
    unsigned short* vtb  = kbuf + 6291456;                 // [4][768][2048]
    unsigned short* ffb  = kbuf;                           // [8192][3072] over k/vt/extra

    const size_t gemm_lds = 3 * 32768;                     // 96 KB tri-buffer

    dim3 tb(32, 8);
    tcvt4_kernel<<<dim3(24, 24, 4), tb, 0, stream>>>(Wq, Wk, Wv, Wo, wqkv_t);
    tcvt_kernel<<<dim3(96, 24), tb, 0, stream>>>(W1, w1_t, 768, 3072);
    tcvt_kernel<<<dim3(24, 96), tb, 0, stream>>>(W2, w2_t, 3072, 768);

    ln_kernel<<<8192, 256, 0, stream>>>(x, g1, be1, hbuf);

    // fused QKV: N = 2304, routes Q->qbuf, K->kbuf, V->vtb(transposed)
    gemm512<4><<<64 * 18, 512, gemm_lds, stream>>>(
        hbuf, wqkv_t, bq, bk, bv, nullptr, qbuf, kbuf, vtb, 2304, 768, 18);

    attn_kernel<<<1536, 256, 0, stream>>>(qbuf, kbuf, vtb, hbuf);   // ctx -> hbuf

    gemm512<3><<<64 * 6, 512, gemm_lds, stream>>>(
        hbuf, wo_t, bo, nullptr, nullptr, x, x2, nullptr, nullptr, 768, 768, 6);

    ln_kernel<<<8192, 256, 0, stream>>>(x2, g2, be2, qbuf);         // h2 -> qbuf

    gemm512<2><<<64 * 24, 512, gemm_lds, stream>>>(
        qbuf, w1_t, b1, nullptr, nullptr, nullptr, ffb, nullptr, nullptr, 3072, 768, 24);

    gemm512<3><<<64 * 6, 512, gemm_lds, stream>>>(
        ffb, w2_t, b2, nullptr, nullptr, x2, out, nullptr, nullptr, 768, 3072, 6);
}

// Round 5
// 257.637 us; speedup vs baseline: 1.0701x; 1.0701x over previous
//
#include <hip/hip_runtime.h>
#include <hip/hip_bf16.h>

#define B_  4
#define T_  2048
#define D_  768
#define H_  12
#define DH_ 64
#define FF_ 3072

typedef __attribute__((ext_vector_type(8))) short bf16x8;
typedef __attribute__((ext_vector_type(4))) float f32x4;
typedef __attribute__((ext_vector_type(4))) unsigned short us4;

#define MFMA16(a, b, c) __builtin_amdgcn_mfma_f32_16x16x32_bf16((a), (b), (c), 0, 0, 0)

__device__ __forceinline__ unsigned short f2bf(float f) {
    union { float f; unsigned u; } v; v.f = f;
    unsigned r = v.u + 0x7fffu + ((v.u >> 16) & 1u);
    return (unsigned short)(r >> 16);
}

// async global->LDS, 16B per lane. LDS dest must be wave-uniform; HW adds lane*16.
__device__ __forceinline__ void gload_lds16(const unsigned short* gp, unsigned short* lp) {
    __builtin_amdgcn_global_load_lds(
        (const __attribute__((address_space(1))) unsigned int*)gp,
        (__attribute__((address_space(3))) unsigned int*)lp,
        16, 0, 0);
}

// ---------------- weight convert + transpose: src[K][N] f32 -> dst[N][K] bf16 ----------
__global__ __launch_bounds__(256) void tcvt_kernel(
    const float* __restrict__ src, unsigned short* __restrict__ dst, int K, int N)
{
    __shared__ float tile[32][33];
    const int bx = blockIdx.x * 32;  // N dim
    const int by = blockIdx.y * 32;  // K dim
    const int tx = threadIdx.x, ty = threadIdx.y;  // 32 x 8
#pragma unroll
    for (int i = 0; i < 32; i += 8)
        tile[ty + i][tx] = src[(size_t)(by + ty + i) * N + bx + tx];
    __syncthreads();
#pragma unroll
    for (int i = 0; i < 32; i += 8)
        dst[(size_t)(bx + ty + i) * K + by + tx] = f2bf(tile[tx][ty + i]);
}

// batched version for the four 768x768 weights (Wq,Wk,Wv,Wo -> contiguous dst)
__global__ __launch_bounds__(256) void tcvt4_kernel(
    const float* __restrict__ s0, const float* __restrict__ s1,
    const float* __restrict__ s2, const float* __restrict__ s3,
    unsigned short* __restrict__ dst)
{
    __shared__ float tile[32][33];
    const int z = blockIdx.z;
    const float* src = (z == 0) ? s0 : (z == 1) ? s1 : (z == 2) ? s2 : s3;
    unsigned short* d = dst + (size_t)z * 589824;
    const int bx = blockIdx.x * 32;
    const int by = blockIdx.y * 32;
    const int tx = threadIdx.x, ty = threadIdx.y;
#pragma unroll
    for (int i = 0; i < 32; i += 8)
        tile[ty + i][tx] = src[(size_t)(by + ty + i) * 768 + bx + tx];
    __syncthreads();
#pragma unroll
    for (int i = 0; i < 32; i += 8)
        d[(size_t)(bx + ty + i) * 768 + by + tx] = f2bf(tile[tx][ty + i]);
}

// ---------------- LayerNorm: fp32 in -> bf16 out ----------------
__global__ __launch_bounds__(256) void ln_kernel(
    const float* __restrict__ x, const float* __restrict__ g,
    const float* __restrict__ be, unsigned short* __restrict__ out)
{
    const int row = blockIdx.x;
    const int t = threadIdx.x;
    const float* xr = x + (size_t)row * D_;
    float v0 = xr[t], v1 = xr[t + 256], v2 = xr[t + 512];
    float s = v0 + v1 + v2;
    float s2 = v0 * v0 + v1 * v1 + v2 * v2;
#pragma unroll
    for (int o = 1; o < 64; o <<= 1) {
        s  += __shfl_xor(s,  o);
        s2 += __shfl_xor(s2, o);
    }
    __shared__ float rs[4], rq[4];
    const int wave = t >> 6;
    if ((t & 63) == 0) { rs[wave] = s; rq[wave] = s2; }
    __syncthreads();
    s  = rs[0] + rs[1] + rs[2] + rs[3];
    s2 = rq[0] + rq[1] + rq[2] + rq[3];
    const float mu = s * (1.0f / D_);
    const float var = s2 * (1.0f / D_) - mu * mu;
    const float rstd = rsqrtf(var + 1e-5f);
    unsigned short* orow = out + (size_t)row * D_;
    orow[t]       = f2bf((v0 - mu) * rstd * g[t]       + be[t]);
    orow[t + 256] = f2bf((v1 - mu) * rstd * g[t + 256] + be[t + 256]);
    orow[t + 512] = f2bf((v2 - mu) * rstd * g[t + 512] + be[t + 512]);
}

// ---------------- GEMM: C[M][N] = A[M][K] * Bt[N][K]^T + bias ----------------
// BM=256, BN=128, BK=32; 512 threads (8 waves as 4x2), wave-tile 64x64 (acc 4x4).
// TRI-buffered (24KB x3 = 72KB -> 2 blocks/CU). 2 phases per K-tile:
//  P0: 6 ds_read (afr0,1 + bfr0..3) | stage 2 A-gloads of tile t+2 | MFMA x8 | barrier
//  P1: 2 ds_read (afr2,3)          | stage 1 B-gload  of tile t+2 | MFMA x8 | vmcnt(3) | barrier
// Counted vmcnt(3): tile t+2's 3 loads stay in flight; never drains mid-loop (T4).
// LDS rows are 32 shorts = 4 x 16B blocks; XOR swizzle key(r) = (r&3)^((r>>2)&3)
// applied on the pre-swizzled global SOURCE (gload dest linear) and on ds_read.
// -> max 2 lanes/bank (free). 1D grid, N-fastest, bijective XCD swizzle.
// MODE 0: bf16 out; MODE 2: gelu->bf16; MODE 3: fp32 = acc+bias+resid;
// MODE 4: fused QKV routing (Q,K bf16 [M][768]; V transposed out3[b][n][t]).
template<int MODE>
__global__ __launch_bounds__(512, 4) void gemm8p(
    const unsigned short* __restrict__ A,
    const unsigned short* __restrict__ Bt,
    const float* __restrict__ bias,
    const float* __restrict__ bias2,
    const float* __restrict__ bias3,
    const float* __restrict__ resid,
    void* __restrict__ outp,
    void* __restrict__ out2,
    void* __restrict__ out3,
    int N, int K, int nTilesN)
{
    extern __shared__ __align__(16) unsigned short lds[];   // 3 x 12288 shorts = 72KB

    // bijective XCD swizzle (m204)
    const int nwg = gridDim.x;
    const int q = nwg >> 3, rr = nwg & 7;
    const int xcd = blockIdx.x & 7, loc = blockIdx.x >> 3;
    const int swz = (xcd < rr ? xcd * (q + 1) : rr * (q + 1) + (xcd - rr) * q) + loc;
    const int m0 = (swz / nTilesN) * 256;
    const int n0 = (swz % nTilesN) * 128;

    const int tid = threadIdx.x;
    const int wv = tid >> 6;
    const int lane = tid & 63;
    const int wr = wv >> 1;          // 0..3 (M)
    const int wc = wv & 1;           // 0..1 (N)

    f32x4 zero4 = {0.0f, 0.0f, 0.0f, 0.0f};
    f32x4 acc[4][4];
#pragma unroll
    for (int i = 0; i < 4; ++i)
#pragma unroll
        for (int j = 0; j < 4; ++j) acc[i][j] = zero4;

    // ---- staging setup: wave wv stages A rows [32wv,32wv+32) (2 gloads) + B rows [16wv,16wv+16)
    const int lrow = lane >> 2;                       // 0..15
    const int skey = (lrow & 3) ^ ((lrow >> 2) & 3);  // source-swizzle key
    const int scb  = (lane & 3) ^ skey;               // source col-block
    const unsigned short* pA0 = A  + (size_t)(m0 + wv * 32 + lrow) * K + scb * 8;
    const unsigned short* pA1 = pA0 + (size_t)16 * K;
    const unsigned short* pB  = Bt + (size_t)(n0 + wv * 16 + lrow) * K + scb * 8;
    const int aD0 = wv * 32 * 32;                     // LDS short-offsets (wave-uniform)
    const int aD1 = aD0 + 16 * 32;
    const int bD  = 8192 + wv * 16 * 32;

    // ---- fragment-read setup
    const int fr = lane & 15;
    const int fg = lane >> 4;                         // 0..3
    const int rb = ((fg ^ (fr & 3) ^ ((fr >> 2) & 3)) << 3);
    const int aOff = (wr * 64 + fr) * 32 + rb;        // + mm*512
    const int bOff = 8192 + (wc * 64 + fr) * 32 + rb; // + nn*512

    unsigned short* pc = lds;            // compute (tile t)
    unsigned short* pn = lds + 12288;    // tile t+1
    unsigned short* ps = lds + 24576;    // stage target (tile t+2)

    const int nk = K >> 5;

    // prologue: stage tiles 0 and 1 (pointers advance 32 shorts per tile)
    gload_lds16(pA0, pc + aD0); gload_lds16(pA1, pc + aD1); gload_lds16(pB, pc + bD);
    pA0 += 32; pA1 += 32; pB += 32;
    gload_lds16(pA0, pn + aD0); gload_lds16(pA1, pn + aD1); gload_lds16(pB, pn + bD);
    pA0 += 32; pA1 += 32; pB += 32;
    asm volatile("s_waitcnt vmcnt(3)" ::: "memory");
    __builtin_amdgcn_s_barrier();

    for (int t = 0; t < nk; ++t) {
        const bool st = (t + 2 < nk);
        // ---- P0: reads for m-half 0 + all B frags
        bf16x8 a0 = *(const bf16x8*)(pc + aOff);
        bf16x8 a1 = *(const bf16x8*)(pc + aOff + 512);
        bf16x8 b0 = *(const bf16x8*)(pc + bOff);
        bf16x8 b1 = *(const bf16x8*)(pc + bOff + 512);
        bf16x8 b2 = *(const bf16x8*)(pc + bOff + 1024);
        bf16x8 b3 = *(const bf16x8*)(pc + bOff + 1536);
        if (st) { gload_lds16(pA0, ps + aD0); gload_lds16(pA1, ps + aD1); }
        asm volatile("s_waitcnt lgkmcnt(0)" ::: "memory");
        __builtin_amdgcn_sched_barrier(0);
        __builtin_amdgcn_s_setprio(1);
        acc[0][0] = MFMA16(a0, b0, acc[0][0]);
        acc[0][1] = MFMA16(a0, b1, acc[0][1]);
        acc[0][2] = MFMA16(a0, b2, acc[0][2]);
        acc[0][3] = MFMA16(a0, b3, acc[0][3]);
        acc[1][0] = MFMA16(a1, b0, acc[1][0]);
        acc[1][1] = MFMA16(a1, b1, acc[1][1]);
        acc[1][2] = MFMA16(a1, b2, acc[1][2]);
        acc[1][3] = MFMA16(a1, b3, acc[1][3]);
        __builtin_amdgcn_s_setprio(0);
        __builtin_amdgcn_s_barrier();

        // ---- P1: reads for m-half 1
        bf16x8 a2 = *(const bf16x8*)(pc + aOff + 1024);
        bf16x8 a3 = *(const bf16x8*)(pc + aOff + 1536);
        if (st) { gload_lds16(pB, ps + bD); pA0 += 32; pA1 += 32; pB += 32; }
        asm volatile("s_waitcnt lgkmcnt(0)" ::: "memory");
        __builtin_amdgcn_sched_barrier(0);
        __builtin_amdgcn_s_setprio(1);
        acc[2][0] = MFMA16(a2, b0, acc[2][0]);
        acc[2][1] = MFMA16(a2, b1, acc[2][1]);
        acc[2][2] = MFMA16(a2, b2, acc[2][2]);
        acc[2][3] = MFMA16(a2, b3, acc[2][3]);
        acc[3][0] = MFMA16(a3, b0, acc[3][0]);
        acc[3][1] = MFMA16(a3, b1, acc[3][1]);
        acc[3][2] = MFMA16(a3, b2, acc[3][2]);
        acc[3][3] = MFMA16(a3, b3, acc[3][3]);
        __builtin_amdgcn_s_setprio(0);
        if (st)               asm volatile("s_waitcnt vmcnt(3)" ::: "memory");
        else if (t + 1 < nk)  asm volatile("s_waitcnt vmcnt(0)" ::: "memory");
        __builtin_amdgcn_s_barrier();

        // rotate tri-buffer
        unsigned short* tmp = pc; pc = pn; pn = ps; ps = tmp;
    }

    // ---- epilogue
    const int lc = lane & 15;
    const int lr = (lane >> 4) * 4;
#pragma unroll
    for (int mm = 0; mm < 4; ++mm) {
        const int gm0 = m0 + wr * 64 + mm * 16 + lr;
#pragma unroll
        for (int nn = 0; nn < 4; ++nn) {
            const int gn = n0 + wc * 64 + nn * 16 + lc;
            if (MODE == 4) {
                if (gn < 1536) {
                    const float bv = (gn < 768) ? bias[gn] : bias2[gn - 768];
                    unsigned short* o = (gn < 768) ? (unsigned short*)outp : (unsigned short*)out2;
                    const int col = (gn < 768) ? gn : gn - 768;
#pragma unroll
                    for (int r = 0; r < 4; ++r)
                        o[(size_t)(gm0 + r) * 768 + col] = f2bf(acc[mm][nn][r] + bv);
                } else {
                    const float bv = bias3[gn - 1536];
                    const int b = gm0 / T_;
                    const int tl = gm0 - b * T_;
                    us4 pk;
#pragma unroll
                    for (int r = 0; r < 4; ++r) pk[r] = f2bf(acc[mm][nn][r] + bv);
                    *(us4*)((unsigned short*)out3 + ((size_t)(b * D_ + gn - 1536)) * T_ + tl) = pk;
                }
            } else {
                const float bv = bias[gn];
#pragma unroll
                for (int r = 0; r < 4; ++r) {
                    const int gm = gm0 + r;
                    float v = acc[mm][nn][r] + bv;
                    if (MODE == 0) {
                        ((unsigned short*)outp)[(size_t)gm * N + gn] = f2bf(v);
                    } else if (MODE == 2) {
                        v = 0.5f * v * (1.0f + erff(v * 0.70710678118654752f));
                        ((unsigned short*)outp)[(size_t)gm * N + gn] = f2bf(v);
                    } else if (MODE == 3) {
                        ((float*)outp)[(size_t)gm * N + gn] = v + resid[(size_t)gm * N + gn];
                    }
                }
            }
        }
    }
}

// ---------------- banded flash attention ----------------
// block = 256 threads (4 waves), handles (b, h, 64-query tile)
// K/V window = [t0, t1), KW <= 192
__global__ __launch_bounds__(256) void attn_kernel(
    const unsigned short* __restrict__ Q,    // [B*T][768]
    const unsigned short* __restrict__ Kg,   // [B*T][768]
    const unsigned short* __restrict__ Vt,   // [B][768][T]
    unsigned short* __restrict__ ctx)        // [B*T][768]
{
    __shared__ __align__(16) unsigned short Qs[64][72];
    __shared__ __align__(16) unsigned short KP[192 * 72];   // Ks[192][72], later Ps[64][200]
    __shared__ __align__(16) unsigned short Vts[64][200];

    const int tid = threadIdx.x;
    const int lane = tid & 63;
    const int w = tid >> 6;
    const int bid = blockIdx.x;
    const int qt = bid & 31;
    const int h = (bid >> 5) % H_;
    const int b = bid / (32 * H_);
    const int qs = qt * 64;
    const int t0 = qs >= 64 ? qs - 64 : 0;
    const int t1 = (qs + 128 < T_) ? qs + 128 : T_;
    const int KW = t1 - t0;

    // stage Q (64 rows x 64 cols)
    for (int s = tid; s < 512; s += 256) {
        const int r = s >> 3, c8 = (s & 7) << 3;
        *(uint4*)&Qs[r][c8] =
            *(const uint4*)&Q[((size_t)(b * T_ + qs + r)) * D_ + h * DH_ + c8];
    }
    // stage K (192 rows x 64), zero-filled beyond window
    unsigned short* Ks = KP;
    for (int s = tid; s < 1536; s += 256) {
        const int r = s >> 3, c8 = (s & 7) << 3;
        uint4 val = {0, 0, 0, 0};
        if (r < KW)
            val = *(const uint4*)&Kg[((size_t)(b * T_ + t0 + r)) * D_ + h * DH_ + c8];
        *(uint4*)&Ks[r * 72 + c8] = val;
    }
    // stage V^T (64 dh-rows x 192 key-cols), zero-filled beyond window
    for (int s = tid; s < 1536; s += 256) {
        const int r = s / 24, c8 = (s % 24) << 3;
        uint4 val = {0, 0, 0, 0};
        if (c8 < KW)
            val = *(const uint4*)&Vt[((size_t)((b * H_ + h) * DH_ + r)) * T_ + t0 + c8];
        *(uint4*)&Vts[r][c8] = val;
    }
    __syncthreads();

    // S = Q K^T : per wave 16 q-rows x 192 keys, 12 col-frags, K=64 (2 ksteps)
    f32x4 zero4 = {0.0f, 0.0f, 0.0f, 0.0f};
    f32x4 sa[12];
#pragma unroll
    for (int i = 0; i < 12; ++i) sa[i] = zero4;
#pragma unroll
    for (int ks = 0; ks < 2; ++ks) {
        const bf16x8 aq = *(const bf16x8*)&Qs[w * 16 + (lane & 15)][ks * 32 + (lane >> 4) * 8];
#pragma unroll
        for (int cf = 0; cf < 12; ++cf) {
            const bf16x8 bk = *(const bf16x8*)&Ks[(cf * 16 + (lane & 15)) * 72 + ks * 32 + (lane >> 4) * 8];
            sa[cf] = MFMA16(aq, bk, sa[cf]);
        }
    }
    __syncthreads();   // everyone done reading Ks before Ps overwrites it

    // mask + softmax (row = q, spread over 16 lanes x 12 frags)
    const int lq = w * 16 + (lane >> 4) * 4;
    float mx[4] = {-1e30f, -1e30f, -1e30f, -1e30f};
#pragma unroll
    for (int cf = 0; cf < 12; ++cf) {
        const int key = t0 + cf * 16 + (lane & 15);
#pragma unroll
        for (int r = 0; r < 4; ++r) {
            const int dd = (qs + lq + r) - key;
            const bool ok = (key < t1) && (dd <= 64) && (dd >= -64);
            const float sv = ok ? sa[cf][r] * 0.125f : -1e30f;
            sa[cf][r] = sv;
            mx[r] = fmaxf(mx[r], sv);
        }
    }
#pragma unroll
    for (int r = 0; r < 4; ++r)
#pragma unroll
        for (int o = 1; o < 16; o <<= 1)
            mx[r] = fmaxf(mx[r], __shfl_xor(mx[r], o));

    unsigned short* Ps = KP;   // [64][200]
    float sm[4] = {0.0f, 0.0f, 0.0f, 0.0f};
#pragma unroll
    for (int cf = 0; cf < 12; ++cf) {
#pragma unroll
        for (int r = 0; r < 4; ++r) {
            const float p = __expf(sa[cf][r] - mx[r]);   // masked -> 0
            sm[r] += p;
            Ps[(lq + r) * 200 + cf * 16 + (lane & 15)] = f2bf(p);
        }
    }
#pragma unroll
    for (int r = 0; r < 4; ++r)
#pragma unroll
        for (int o = 1; o < 16; o <<= 1)
            sm[r] += __shfl_xor(sm[r], o);

    // O = P V : per wave 16 q-rows x 64 dh, 4 col-frags, K=192 (6 ksteps)
    f32x4 oa[4];
#pragma unroll
    for (int i = 0; i < 4; ++i) oa[i] = zero4;
#pragma unroll
    for (int ks = 0; ks < 6; ++ks) {
        const bf16x8 ap = *(const bf16x8*)&Ps[(w * 16 + (lane & 15)) * 200 + ks * 32 + (lane >> 4) * 8];
#pragma unroll
        for (int nf = 0; nf < 4; ++nf) {
            const bf16x8 bv = *(const bf16x8*)&Vts[nf * 16 + (lane & 15)][ks * 32 + (lane >> 4) * 8];
            oa[nf] = MFMA16(ap, bv, oa[nf]);
        }
    }
#pragma unroll
    for (int nf = 0; nf < 4; ++nf) {
#pragma unroll
        for (int r = 0; r < 4; ++r) {
            const float o = oa[nf][r] / sm[r];
            ctx[((size_t)(b * T_ + qs + lq + r)) * D_ + h * DH_ + nf * 16 + (lane & 15)] = f2bf(o);
        }
    }
}

// ---------------- orchestration ----------------
extern "C" void kernel_launch(void* const* d_in, const int* in_sizes, int n_in,
                              void* d_out, int out_size, void* d_ws, size_t ws_size,
                              hipStream_t stream)
{
    const float* x   = (const float*)d_in[0];
    const float* Wq  = (const float*)d_in[1];
    const float* bq  = (const float*)d_in[2];
    const float* Wk  = (const float*)d_in[3];
    const float* bk  = (const float*)d_in[4];
    const float* Wv  = (const float*)d_in[5];
    const float* bv  = (const float*)d_in[6];
    const float* Wo  = (const float*)d_in[7];
    const float* bo  = (const float*)d_in[8];
    const float* W1  = (const float*)d_in[9];
    const float* b1  = (const float*)d_in[10];
    const float* W2  = (const float*)d_in[11];
    const float* b2  = (const float*)d_in[12];
    const float* g1  = (const float*)d_in[13];
    const float* be1 = (const float*)d_in[14];
    const float* g2  = (const float*)d_in[15];
    const float* be2 = (const float*)d_in[16];
    float* out = (float*)d_out;

    // workspace layout (elements):
    // wqkv_t [2304][768] bf16, wo_t, w1_t, w2_t | hbuf | qbuf | x2 f32 | kbuf | vtb | ffb over kbuf..
    unsigned short* wqkv_t = (unsigned short*)d_ws;        // 3 x [768][768]
    unsigned short* wo_t = wqkv_t + 3 * 589824;
    unsigned short* w1_t = wo_t + 589824;                  // [3072][768]
    unsigned short* w2_t = w1_t + 2359296;                 // [768][3072]
    unsigned short* hbuf = w2_t + 2359296;                 // h1, later ctx
    unsigned short* qbuf = hbuf + 6291456;                 // q, later h2
    float* x2 = (float*)(qbuf + 6291456);                  // fp32 [8192][768]
    unsigned short* kbuf = (unsigned short*)(x2 + 6291456);
    unsigned short* vtb  = kbuf + 6291456;                 // [4][768][2048]
    unsigned short* ffb  = kbuf;                           // [8192][3072] over k/vt/extra

    const size_t gemm_lds = 3 * 24576;                     // 72 KB tri-buffer

    dim3 tb(32, 8);
    tcvt4_kernel<<<dim3(24, 24, 4), tb, 0, stream>>>(Wq, Wk, Wv, Wo, wqkv_t);
    tcvt_kernel<<<dim3(96, 24), tb, 0, stream>>>(W1, w1_t, 768, 3072);
    tcvt_kernel<<<dim3(24, 96), tb, 0, stream>>>(W2, w2_t, 3072, 768);

    ln_kernel<<<8192, 256, 0, stream>>>(x, g1, be1, hbuf);

    // fused QKV: N = 2304, routes Q->qbuf, K->kbuf, V->vtb(transposed)
    gemm8p<4><<<32 * 18, 512, gemm_lds, stream>>>(
        hbuf, wqkv_t, bq, bk, bv, nullptr, qbuf, kbuf, vtb, 2304, 768, 18);

    attn_kernel<<<1536, 256, 0, stream>>>(qbuf, kbuf, vtb, hbuf);   // ctx -> hbuf

    gemm8p<3><<<32 * 6, 512, gemm_lds, stream>>>(
        hbuf, wo_t, bo, nullptr, nullptr, x, x2, nullptr, nullptr, 768, 768, 6);

    ln_kernel<<<8192, 256, 0, stream>>>(x2, g2, be2, qbuf);         // h2 -> qbuf

    gemm8p<2><<<32 * 24, 512, gemm_lds, stream>>>(
        qbuf, w1_t, b1, nullptr, nullptr, nullptr, ffb, nullptr, nullptr, 3072, 768, 24);

    gemm8p<3><<<32 * 6, 512, gemm_lds, stream>>>(
        ffb, w2_t, b2, nullptr, nullptr, x2, out, nullptr, nullptr, 768, 3072, 6);
}